// Round 12
// baseline (230.566 us; speedup 1.0000x reference)
//
#include <hip/hip_runtime.h>
#include <hip/hip_bf16.h>
#include <math.h>

#define B 2
#define M 32
#define T 512
#define D 128
#define H 4
#define DK 32
#define NTOK (B*M*T)   /* 32768 rows */

using s16x8 = __attribute__((ext_vector_type(8))) short;
using s16x4 = __attribute__((ext_vector_type(4))) short;
using f32x4 = __attribute__((ext_vector_type(4))) float;

__device__ __forceinline__ short f2bf(float x) {
    union { float f; unsigned u; } a; a.f = x;
    unsigned r = a.u + 0x7fffu + ((a.u >> 16) & 1u);   // RNE
    return (short)(r >> 16);
}
__device__ __forceinline__ unsigned pkbf(float lo, float hi) {
    union { __hip_bfloat162 h; unsigned u; } c;
    c.h = __float22bfloat162_rn(float2{lo, hi});
    return c.u;
}

// ---------------- all weights fp32 -> bf16 in one dispatch ----------------
// dst layout: Wq[0,32768) Wk[32768,65536) Wv[65536,98304) Wfc[98304,131072)
//             W1[131072,262144) W2[262144,393216)
__global__ __launch_bounds__(256) void cvt_all_kernel(const float* __restrict__ Wq, const float* __restrict__ Wk,
                                                      const float* __restrict__ Wv, const float* __restrict__ Wfc,
                                                      const float* __restrict__ W1, const float* __restrict__ W2,
                                                      short* __restrict__ dst)
{
    int i = (blockIdx.x * 256 + threadIdx.x) * 4;
    if (i >= 393216) return;
    const float* src; int off;
    if (i < 131072) {
        int wsel = i >> 15; off = i & 32767;
        src = (wsel == 0) ? Wq : (wsel == 1) ? Wk : (wsel == 2) ? Wv : Wfc;
    } else if (i < 262144) { src = W1; off = i - 131072; }
    else                   { src = W2; off = i - 262144; }
    float4 v = *(const float4*)(src + off);
    ushort4 u;
    u.x = (unsigned short)f2bf(v.x); u.y = (unsigned short)f2bf(v.y);
    u.z = (unsigned short)f2bf(v.z); u.w = (unsigned short)f2bf(v.w);
    *(ushort4*)(dst + i) = u;
}

// ---------------- LayerNorm (final only): one wave per row of 128, fp32 out ----------------
__global__ __launch_bounds__(256) void ln_kernel(const float* __restrict__ in, float* __restrict__ outf,
                                                 const float* __restrict__ g, const float* __restrict__ b)
{
    int wave = threadIdx.x >> 6;
    int lane = threadIdx.x & 63;
    int row  = blockIdx.x * 4 + wave;
    const float* rp = in + (size_t)row * D;
    float v0 = rp[lane], v1 = rp[lane + 64];
    float s = v0 + v1, ss = v0 * v0 + v1 * v1;
    #pragma unroll
    for (int off = 32; off; off >>= 1) { s += __shfl_xor(s, off); ss += __shfl_xor(ss, off); }
    float mu  = s * (1.0f / 128.0f);
    float var = ss * (1.0f / 128.0f) - mu * mu;
    float rs  = rsqrtf(var + 1e-6f);
    float* op = outf + (size_t)row * D;
    op[lane]      = (v0 - mu) * rs * g[lane]      + b[lane];
    op[lane + 64] = (v1 - mu) * rs * g[lane + 64] + b[lane + 64];
}

#define KP 136

// LN staging helper: computes LN of row (rowBase+sr), cols sq*32..+31, writes bf16 into As.
#define LN_STAGE(XPTR, GPTR, BEPTR)                                              \
    {                                                                            \
        const float* xp = (XPTR) + (size_t)(rowBase + sr) * D + sq * 32;         \
        float4 xv[8];                                                            \
        _Pragma("unroll")                                                        \
        for (int j = 0; j < 8; j++) xv[j] = *(const float4*)(xp + j * 4);        \
        float s = 0.0f, ss = 0.0f;                                               \
        _Pragma("unroll")                                                        \
        for (int j = 0; j < 8; j++) {                                            \
            s  += xv[j].x + xv[j].y + xv[j].z + xv[j].w;                         \
            ss += xv[j].x*xv[j].x + xv[j].y*xv[j].y + xv[j].z*xv[j].z + xv[j].w*xv[j].w; \
        }                                                                        \
        s  += __shfl_xor(s, 1);  s  += __shfl_xor(s, 2);                         \
        ss += __shfl_xor(ss, 1); ss += __shfl_xor(ss, 2);                        \
        float mu  = s * (1.0f / 128.0f);                                         \
        float var = ss * (1.0f / 128.0f) - mu * mu;                              \
        float rs  = rsqrtf(var + 1e-6f);                                         \
        const float* gp  = (GPTR) + sq * 32;                                     \
        const float* bep = (BEPTR) + sq * 32;                                    \
        short* asd = &As[sr * KP + sq * 32];                                     \
        _Pragma("unroll")                                                        \
        for (int c = 0; c < 4; c++) {                                            \
            float4 a0 = xv[2*c], a1 = xv[2*c+1];                                 \
            float4 g0 = *(const float4*)(gp + c * 8);                            \
            float4 g1 = *(const float4*)(gp + c * 8 + 4);                        \
            float4 b0 = *(const float4*)(bep + c * 8);                           \
            float4 b1 = *(const float4*)(bep + c * 8 + 4);                       \
            union { unsigned u[4]; s16x8 v8; } pu;                               \
            pu.u[0] = pkbf((a0.x-mu)*rs*g0.x+b0.x, (a0.y-mu)*rs*g0.y+b0.y);      \
            pu.u[1] = pkbf((a0.z-mu)*rs*g0.z+b0.z, (a0.w-mu)*rs*g0.w+b0.w);      \
            pu.u[2] = pkbf((a1.x-mu)*rs*g1.x+b1.x, (a1.y-mu)*rs*g1.y+b1.y);      \
            pu.u[3] = pkbf((a1.z-mu)*rs*g1.z+b1.z, (a1.w-mu)*rs*g1.w+b1.w);      \
            *(s16x8*)(asd + c * 8) = pu.v8;                                      \
        }                                                                        \
    }

// ---------------- Fused LN + Q/K/V projections: A + ALL THREE W tiles staged once ----------------
__global__ __launch_bounds__(512) void qkv_ln_kernel(const float* __restrict__ X,
                                                     const float* __restrict__ g, const float* __restrict__ be,
                                                     const short* __restrict__ Wq, const short* __restrict__ Wk,
                                                     const short* __restrict__ Wv,
                                                     const float* __restrict__ bq, const float* __restrict__ bk,
                                                     const float* __restrict__ bv,
                                                     short* __restrict__ Qo, short* __restrict__ Ko,
                                                     short* __restrict__ Vo)
{
    __shared__ short As[128 * KP];
    __shared__ short Ws[3][128 * KP];
    const int tid = threadIdx.x;
    const int rowBase = blockIdx.x * 128;
    const int sr = tid >> 2, sq = tid & 3;
    const int w = tid >> 6, l = tid & 63;
    const int lg = l >> 4, lr = l & 15;
    const int wr = w >> 2, wc = w & 3;

    const short* wsrc[3] = { Wq, Wk, Wv };
    const float* bsrc[3] = { bq, bk, bv };
    short*       osrc[3] = { Qo, Ko, Vo };

    #pragma unroll
    for (int gsel = 0; gsel < 3; gsel++) {
        const short* wp = wsrc[gsel] + (size_t)sr * D + sq * 32;
        short* wsd = &Ws[gsel][sr * KP + sq * 32];
        #pragma unroll
        for (int i = 0; i < 4; i++) *(s16x8*)(wsd + i * 8) = *(const s16x8*)(wp + i * 8);
    }
    LN_STAGE(X, g, be)
    __syncthreads();

    for (int gsel = 0; gsel < 3; gsel++) {
        f32x4 acc[4][2];
        #pragma unroll
        for (int qi = 0; qi < 4; qi++)
            #pragma unroll
            for (int nj = 0; nj < 2; nj++)
                acc[qi][nj] = (f32x4){0.0f, 0.0f, 0.0f, 0.0f};
        #pragma unroll
        for (int kk = 0; kk < 4; kk++) {
            s16x8 af[4], bfr[2];
            #pragma unroll
            for (int qi = 0; qi < 4; qi++)
                af[qi] = *(const s16x8*)&As[(wr * 64 + qi * 16 + lr) * KP + kk * 32 + lg * 8];
            #pragma unroll
            for (int nj = 0; nj < 2; nj++)
                bfr[nj] = *(const s16x8*)&Ws[gsel][(wc * 32 + nj * 16 + lr) * KP + kk * 32 + lg * 8];
            #pragma unroll
            for (int qi = 0; qi < 4; qi++)
                #pragma unroll
                for (int nj = 0; nj < 2; nj++)
                    acc[qi][nj] = __builtin_amdgcn_mfma_f32_16x16x32_bf16(af[qi], bfr[nj], acc[qi][nj], 0, 0, 0);
        }
        #pragma unroll
        for (int nj = 0; nj < 2; nj++) {
            int col = wc * 32 + nj * 16 + lr;
            float bb = bsrc[gsel][col];
            #pragma unroll
            for (int qi = 0; qi < 4; qi++) {
                #pragma unroll
                for (int rr = 0; rr < 4; rr++) {
                    int row = rowBase + wr * 64 + qi * 16 + lg * 4 + rr;
                    osrc[gsel][(size_t)row * D + col] = f2bf(acc[qi][nj][rr] + bb);
                }
            }
        }
    }
}

// ---------------- Fused MLP: LN2 + W1/ReLU + W2 + residual; H lives only in LDS ----------------
// 64-row tile, 512 threads (8 waves). LDS: As 17.4K + Hs 66.6K + Ws 34.8K = 118.8 KB.
#define HP 520
__global__ __launch_bounds__(512) void mlp_ln_kernel(const float* __restrict__ X,
                                                     const float* __restrict__ g, const float* __restrict__ be,
                                                     const short* __restrict__ W1, const float* __restrict__ b1,
                                                     const short* __restrict__ W2, const float* __restrict__ b2,
                                                     float* __restrict__ Xout)
{
    __shared__ short As[64 * KP];
    __shared__ short Hs[64 * HP];
    __shared__ short Ws[128 * KP];
    const int tid = threadIdx.x;
    const int rowBase = blockIdx.x * 64;
    const int w = tid >> 6, l = tid & 63;
    const int lg = l >> 4, lr = l & 15;

    if (tid < 256) {
        const int sr = tid >> 2, sq = tid & 3;
        LN_STAGE(X, g, be)
    } else {
        // stage first W1 chunk (128 rows x 128): 2 half-rows per thread
        int t2 = tid - 256;
        int r = t2 >> 1, hh = t2 & 1;
        const short* p = W1 + (size_t)r * D + hh * 64;
        short* d2 = &Ws[r * KP + hh * 64];
        #pragma unroll
        for (int i = 0; i < 8; i++) *(s16x8*)(d2 + i * 8) = *(const s16x8*)(p + i * 8);
    }
    __syncthreads();

    const int swr = tid >> 2, swq = tid & 3;   // all-thread weight staging: 128 rows x 4 quarters

    // ---- phase 1: Hs = relu(LN(X) . W1^T + b1), 4 chunks of 128 cols ----
    for (int ct = 0; ct < 4; ct++) {
        f32x4 hacc[4];
        #pragma unroll
        for (int qi = 0; qi < 4; qi++) hacc[qi] = (f32x4){0.0f, 0.0f, 0.0f, 0.0f};
        #pragma unroll
        for (int kk = 0; kk < 4; kk++) {
            s16x8 bf = *(const s16x8*)&Ws[(w * 16 + lr) * KP + kk * 32 + lg * 8];
            #pragma unroll
            for (int qi = 0; qi < 4; qi++) {
                s16x8 af = *(const s16x8*)&As[(qi * 16 + lr) * KP + kk * 32 + lg * 8];
                hacc[qi] = __builtin_amdgcn_mfma_f32_16x16x32_bf16(af, bf, hacc[qi], 0, 0, 0);
            }
        }
        __syncthreads();   // all reads of Ws done
        {
            // stage next chunk: W1 ct+1, or W2 kt=0 after the last ct
            const short* p = (ct < 3) ? (W1 + (size_t)((ct + 1) * 128 + swr) * D + swq * 32)
                                      : (W2 + (size_t)swr * 512 + swq * 32);
            short* d2 = &Ws[swr * KP + swq * 32];
            #pragma unroll
            for (int i = 0; i < 4; i++) *(s16x8*)(d2 + i * 8) = *(const s16x8*)(p + i * 8);
        }
        int col = ct * 128 + w * 16 + lr;
        float bb = b1[col];
        #pragma unroll
        for (int qi = 0; qi < 4; qi++) {
            #pragma unroll
            for (int rr = 0; rr < 4; rr++) {
                int hrow = qi * 16 + lg * 4 + rr;
                Hs[hrow * HP + col] = f2bf(fmaxf(hacc[qi][rr] + bb, 0.0f));
            }
        }
        __syncthreads();   // new Ws + this ct's Hs visible
    }

    // ---- phase 2: X += Hs . W2^T + b2 (K=512 in 4 chunks) ----
    f32x4 acc[4];
    #pragma unroll
    for (int qi = 0; qi < 4; qi++) acc[qi] = (f32x4){0.0f, 0.0f, 0.0f, 0.0f};
    for (int kt = 0; kt < 4; kt++) {
        #pragma unroll
        for (int kk = 0; kk < 4; kk++) {
            s16x8 bf = *(const s16x8*)&Ws[(w * 16 + lr) * KP + kk * 32 + lg * 8];
            #pragma unroll
            for (int qi = 0; qi < 4; qi++) {
                s16x8 af = *(const s16x8*)&Hs[(qi * 16 + lr) * HP + kt * 128 + kk * 32 + lg * 8];
                acc[qi] = __builtin_amdgcn_mfma_f32_16x16x32_bf16(af, bf, acc[qi], 0, 0, 0);
            }
        }
        if (kt < 3) {
            __syncthreads();
            const short* p = W2 + (size_t)swr * 512 + (kt + 1) * 128 + swq * 32;
            short* d2 = &Ws[swr * KP + swq * 32];
            #pragma unroll
            for (int i = 0; i < 4; i++) *(s16x8*)(d2 + i * 8) = *(const s16x8*)(p + i * 8);
            __syncthreads();
        }
    }

    int col = w * 16 + lr;
    float bb2 = b2[col];
    #pragma unroll
    for (int qi = 0; qi < 4; qi++) {
        #pragma unroll
        for (int rr = 0; rr < 4; rr++) {
            int row = rowBase + qi * 16 + lg * 4 + rr;
            size_t o = (size_t)row * D + col;
            Xout[o] = acc[qi][rr] + bb2 + Xout[o];
        }
    }
}

// ---------------- bf16 MFMA GEMM (FC): out = A . W^T + bias + res ----------------
template<int DIN>
__global__ __launch_bounds__(512) void gemm_bf16_kernel(const short* __restrict__ A, const short* __restrict__ W,
                                                        const float* __restrict__ bias, const float* __restrict__ res,
                                                        float* __restrict__ outf, int Dout)
{
    __shared__ short As[128 * KP];
    __shared__ short Ws[128 * KP];
    const int tid = threadIdx.x;
    const int rowBase = blockIdx.y * 128;
    const int colBase = blockIdx.x * 128;
    const int sr = tid >> 2, sq = tid & 3;
    const int w = tid >> 6, l = tid & 63;
    const int lg = l >> 4, lr = l & 15;
    const int wr = w >> 2, wc = w & 3;

    f32x4 acc[4][2];
    #pragma unroll
    for (int qi = 0; qi < 4; qi++)
        #pragma unroll
        for (int nj = 0; nj < 2; nj++)
            acc[qi][nj] = (f32x4){0.0f, 0.0f, 0.0f, 0.0f};

    const short* ap = A + (size_t)(rowBase + sr) * DIN + sq * 32;
    const short* wp = W + (size_t)(colBase + sr) * DIN + sq * 32;
    short* asd = &As[sr * KP + sq * 32];
    short* wsd = &Ws[sr * KP + sq * 32];

    #pragma unroll
    for (int kt = 0; kt < DIN / 128; kt++) {
        s16x8 av[4], wv[4];
        #pragma unroll
        for (int i = 0; i < 4; i++) {
            av[i] = *(const s16x8*)(ap + kt * 128 + i * 8);
            wv[i] = *(const s16x8*)(wp + kt * 128 + i * 8);
        }
        if (kt) __syncthreads();
        #pragma unroll
        for (int i = 0; i < 4; i++) {
            *(s16x8*)(asd + i * 8) = av[i];
            *(s16x8*)(wsd + i * 8) = wv[i];
        }
        __syncthreads();
        #pragma unroll
        for (int kk = 0; kk < 4; kk++) {
            s16x8 af[4], bfr[2];
            #pragma unroll
            for (int qi = 0; qi < 4; qi++)
                af[qi] = *(const s16x8*)&As[(wr * 64 + qi * 16 + lr) * KP + kk * 32 + lg * 8];
            #pragma unroll
            for (int nj = 0; nj < 2; nj++)
                bfr[nj] = *(const s16x8*)&Ws[(wc * 32 + nj * 16 + lr) * KP + kk * 32 + lg * 8];
            #pragma unroll
            for (int qi = 0; qi < 4; qi++)
                #pragma unroll
                for (int nj = 0; nj < 2; nj++)
                    acc[qi][nj] = __builtin_amdgcn_mfma_f32_16x16x32_bf16(af[qi], bfr[nj], acc[qi][nj], 0, 0, 0);
        }
    }

    #pragma unroll
    for (int nj = 0; nj < 2; nj++) {
        int col = colBase + wc * 32 + nj * 16 + lr;
        float bb = bias[col];
        #pragma unroll
        for (int qi = 0; qi < 4; qi++) {
            #pragma unroll
            for (int rr = 0; rr < 4; rr++) {
                int row = rowBase + wr * 64 + qi * 16 + lg * 4 + rr;
                size_t o = (size_t)row * Dout + col;
                outf[o] = acc[qi][nj][rr] + bb + res[o];
            }
        }
    }
}

// ---------------- Context attention via banded MFMA (window L=16, d=128) ----------------
#define XSP 136
#define XTP 84
__global__ __launch_bounds__(256) void ctx_mfma_kernel(const short* __restrict__ in0, short* __restrict__ out0,
                                                       const short* __restrict__ in1, short* __restrict__ out1)
{
    __shared__ short Xs[80 * XSP];
    __shared__ short Xt[128 * XTP];

    const short* in  = blockIdx.y ? in1 : in0;
    short*       out = blockIdx.y ? out1 : out0;
    int bm = blockIdx.x >> 3;
    int t0 = (blockIdx.x & 7) * 64;
    int tid = threadIdx.x;
    const short* base = in + (size_t)bm * T * D;

    #pragma unroll
    for (int it = 0; it < 5; it++) {
        int idx = it * 256 + tid;
        int row = idx >> 4, c16 = idx & 15;
        int t = t0 - 16 + row;
        s16x8 v = {0, 0, 0, 0, 0, 0, 0, 0};
        if (t >= 0) v = *(const s16x8*)(base + (size_t)t * D + c16 * 8);
        *(s16x8*)&Xs[row * XSP + c16 * 8] = v;
    }
    __syncthreads();
    #pragma unroll
    for (int it = 0; it < 5; it++) {
        int task = it * 256 + tid;
        int g = task / 80, row = task % 80;
        s16x8 v = *(const s16x8*)&Xs[row * XSP + g * 8];
        #pragma unroll
        for (int j = 0; j < 8; j++) Xt[(g * 8 + j) * XTP + row] = v[j];
    }
    __syncthreads();

    int w = tid >> 6, l = tid & 63;
    int lg = l >> 4, lr = l & 15;
    f32x4 zacc = {0.0f, 0.0f, 0.0f, 0.0f};
    const float C1 = 0.0883883476483184f * 1.4426950408889634f;   // (1/sqrt(128))*log2e

    s16x8 qf[4];
    #pragma unroll
    for (int kd = 0; kd < 4; kd++)
        qf[kd] = *(const s16x8*)&Xs[(16 + w * 16 + lr) * XSP + kd * 32 + lg * 8];

    f32x4 sacc[2];
    #pragma unroll
    for (int s = 0; s < 2; s++) {
        f32x4 a = zacc;
        #pragma unroll
        for (int kd = 0; kd < 4; kd++) {
            s16x8 kf = *(const s16x8*)&Xs[(w * 16 + s * 16 + lr) * XSP + kd * 32 + lg * 8];
            a = __builtin_amdgcn_mfma_f32_16x16x32_bf16(kf, qf[kd], a, 0, 0, 0);
        }
        sacc[s] = a;
    }

    float p[2][4];
    float mx = -1e30f;
    #pragma unroll
    for (int s = 0; s < 2; s++)
        #pragma unroll
        for (int r = 0; r < 4; r++) {
            int dlt = s * 16 + lg * 4 + r - 16 - lr;   // k - q
            float val = (dlt >= -15 && dlt <= 0) ? sacc[s][r] : -1e30f;
            p[s][r] = val;
            mx = fmaxf(mx, val);
        }
    mx = fmaxf(mx, __shfl_xor(mx, 16));
    mx = fmaxf(mx, __shfl_xor(mx, 32));
    float mc = mx * C1;
    float ps = 0.0f;
    #pragma unroll
    for (int s = 0; s < 2; s++)
        #pragma unroll
        for (int r = 0; r < 4; r++) {
            float e = exp2f(fmaf(p[s][r], C1, -mc));
            p[s][r] = e;
            ps += e;
        }
    ps += __shfl_xor(ps, 16);
    ps += __shfl_xor(ps, 32);

    union { unsigned u[4]; s16x8 v8; } pu;
    pu.u[0] = pkbf(p[0][0], p[0][1]);
    pu.u[1] = pkbf(p[0][2], p[0][3]);
    pu.u[2] = pkbf(p[1][0], p[1][1]);
    pu.u[3] = pkbf(p[1][2], p[1][3]);
    s16x8 pf = pu.v8;

    float rl = 1.0f / ps;
    short* op = out + (size_t)(bm * T + t0 + w * 16 + lr) * D;
    #pragma unroll
    for (int dt = 0; dt < 8; dt++) {
        const short* vb = &Xt[(dt * 16 + lr) * XTP + w * 16 + lg * 4];
        s16x4 a = *(const s16x4*)(vb);
        s16x4 b = *(const s16x4*)(vb + 16);
        s16x8 vf = __builtin_shufflevector(a, b, 0, 1, 2, 3, 4, 5, 6, 7);
        f32x4 Oa = __builtin_amdgcn_mfma_f32_16x16x32_bf16(vf, pf, zacc, 0, 0, 0);
        union { unsigned u[2]; ushort4 s4; } ou;
        ou.u[0] = pkbf(Oa[0] * rl, Oa[1] * rl);
        ou.u[1] = pkbf(Oa[2] * rl, Oa[3] * rl);
        *(ushort4*)(op + dt * 16 + lg * 4) = ou.s4;
    }
}

// ---------------- Full attention per (b,m,h): fixed-max bf16 MFMA flash, 16 waves ----------------
#define KPAD 40
#define VTP  520
__global__ __launch_bounds__(1024) void attn_mfma_kernel(const short* __restrict__ q, const short* __restrict__ k,
                                                         const short* __restrict__ v, short* __restrict__ out)
{
    __shared__ short Ks[512 * KPAD];
    __shared__ short Vt[32 * VTP];

    int h  = blockIdx.x & 3;
    int bm = blockIdx.x >> 2;
    int tid = threadIdx.x;
    size_t headoff = (size_t)(bm * T) * D + h * DK;

    {
        int row = tid >> 1, half = tid & 1;
        const s16x8* kp8 = (const s16x8*)(k + headoff + (size_t)row * D + half * 16);
        s16x8 k0 = kp8[0], k1 = kp8[1];
        short* kd = &Ks[row * KPAD + half * 16];
        *(s16x8*)(kd)     = k0;
        *(s16x8*)(kd + 8) = k1;
        const s16x8* vp8 = (const s16x8*)(v + headoff + (size_t)row * D + half * 16);
        s16x8 v0 = vp8[0], v1 = vp8[1];
        #pragma unroll
        for (int d = 0; d < 8; d++) {
            Vt[(half * 16 + d) * VTP + row]     = v0[d];
            Vt[(half * 16 + 8 + d) * VTP + row] = v1[d];
        }
    }
    __syncthreads();

    int w = tid >> 6, l = tid & 63;
    int lg = l >> 4, lr = l & 15;
    int qw = w * 32;

    s16x8 qf[2];
    #pragma unroll
    for (int qi = 0; qi < 2; qi++)
        qf[qi] = *(const s16x8*)(q + headoff + (size_t)(qw + qi * 16 + lr) * D + lg * 8);

    f32x4 Oa[2][2];
    float lrow[2];
    #pragma unroll
    for (int qi = 0; qi < 2; qi++) {
        lrow[qi] = 0.0f;
        #pragma unroll
        for (int r = 0; r < 4; r++) { Oa[qi][0][r] = 0.0f; Oa[qi][1][r] = 0.0f; }
    }
    const float C1 = 0.17677669529663689f * 1.4426950408889634f;   // (1/sqrt(32))*log2e
    f32x4 zacc = {0.0f, 0.0f, 0.0f, 0.0f};

    for (int kt = 0; kt < 8; kt++) {
        int kb = kt * 64;
        s16x8 kf[2][2];
        #pragma unroll
        for (int s = 0; s < 2; s++)
            #pragma unroll
            for (int hh = 0; hh < 2; hh++)
                kf[s][hh] = *(const s16x8*)&Ks[(kb + s * 32 + hh * 16 + lr) * KPAD + lg * 8];
        s16x8 vf[2][2];
        #pragma unroll
        for (int dh = 0; dh < 2; dh++)
            #pragma unroll
            for (int s = 0; s < 2; s++) {
                const short* vb = &Vt[(dh * 16 + lr) * VTP + kb + s * 32 + lg * 4];
                s16x4 a = *(const s16x4*)(vb);
                s16x4 b = *(const s16x4*)(vb + 16);
                vf[dh][s] = __builtin_shufflevector(a, b, 0, 1, 2, 3, 4, 5, 6, 7);
            }
        #pragma unroll
        for (int qi = 0; qi < 2; qi++) {
            f32x4 sa[2][2];
            #pragma unroll
            for (int s = 0; s < 2; s++)
                #pragma unroll
                for (int hh = 0; hh < 2; hh++)
                    sa[s][hh] = __builtin_amdgcn_mfma_f32_16x16x32_bf16(kf[s][hh], qf[qi], zacc, 0, 0, 0);
            float p[2][8];
            float ps = 0.0f;
            #pragma unroll
            for (int s = 0; s < 2; s++)
                #pragma unroll
                for (int hh = 0; hh < 2; hh++)
                    #pragma unroll
                    for (int r = 0; r < 4; r++) {
                        float e = exp2f(sa[s][hh][r] * C1);
                        p[s][hh * 4 + r] = e;
                        ps += e;
                    }
            lrow[qi] += ps;
            s16x8 pf[2];
            #pragma unroll
            for (int s = 0; s < 2; s++) {
                union { unsigned u[4]; s16x8 v8; } pu;
                pu.u[0] = pkbf(p[s][0], p[s][1]);
                pu.u[1] = pkbf(p[s][2], p[s][3]);
                pu.u[2] = pkbf(p[s][4], p[s][5]);
                pu.u[3] = pkbf(p[s][6], p[s][7]);
                pf[s] = pu.v8;
            }
            #pragma unroll
            for (int dh = 0; dh < 2; dh++)
                #pragma unroll
                for (int s = 0; s < 2; s++)
                    Oa[qi][dh] = __builtin_amdgcn_mfma_f32_16x16x32_bf16(vf[dh][s], pf[s], Oa[qi][dh], 0, 0, 0);
        }
    }

    #pragma unroll
    for (int qi = 0; qi < 2; qi++) {
        float lv = lrow[qi];
        lv += __shfl_xor(lv, 16);
        lv += __shfl_xor(lv, 32);
        float rl = 1.0f / lv;
        int qrow = qw + qi * 16 + lr;
        short* op = out + headoff + (size_t)qrow * D;
        #pragma unroll
        for (int dh = 0; dh < 2; dh++) {
            union { unsigned u[2]; ushort4 s4; } ou;
            ou.u[0] = pkbf(Oa[qi][dh][0] * rl, Oa[qi][dh][1] * rl);
            ou.u[1] = pkbf(Oa[qi][dh][2] * rl, Oa[qi][dh][3] * rl);
            *(ushort4*)(op + dh * 16 + lg * 4) = ou.s4;
        }
    }
}

// ---------------- Cross-m attention per (b,t) via MFMA: 4 waves = 4 heads of 32x32 ----------------
#define CXP 136
#define CTP 36
__global__ __launch_bounds__(256) void crossm_mfma_kernel(const short* __restrict__ in, short* __restrict__ out)
{
    __shared__ short Xs[32 * CXP];
    __shared__ short Xt[128 * CTP];
    int b = blockIdx.x >> 9;
    int t = blockIdx.x & 511;
    int tid = threadIdx.x;

    #pragma unroll
    for (int it = 0; it < 2; it++) {
        int idx = it * 256 + tid;
        int m = idx >> 4, c16 = idx & 15;
        s16x8 v = *(const s16x8*)(in + (size_t)((b * M + m) * T + t) * D + c16 * 8);
        *(s16x8*)&Xs[m * CXP + c16 * 8] = v;
    }
    __syncthreads();
    #pragma unroll
    for (int it = 0; it < 2; it++) {
        int task = it * 256 + tid;
        int g = task >> 5, m = task & 31;
        s16x8 v = *(const s16x8*)&Xs[m * CXP + g * 8];
        #pragma unroll
        for (int j = 0; j < 8; j++) Xt[(g * 8 + j) * CTP + m] = v[j];
    }
    __syncthreads();

    int h = tid >> 6, l = tid & 63;
    int lg = l >> 4, lr = l & 15;
    f32x4 zacc = {0.0f, 0.0f, 0.0f, 0.0f};
    const float C1 = 0.17677669529663689f * 1.4426950408889634f;

    s16x8 xf[2];
    #pragma unroll
    for (int i = 0; i < 2; i++)
        xf[i] = *(const s16x8*)&Xs[(i * 16 + lr) * CXP + h * 32 + lg * 8];

    f32x4 sacc[2][2];
    #pragma unroll
    for (int kt = 0; kt < 2; kt++)
        #pragma unroll
        for (int qt = 0; qt < 2; qt++)
            sacc[kt][qt] = __builtin_amdgcn_mfma_f32_16x16x32_bf16(xf[kt], xf[qt], zacc, 0, 0, 0);

    s16x8 pf[2];
    float rl[2];
    #pragma unroll
    for (int qt = 0; qt < 2; qt++) {
        float p[2][4];
        float ps = 0.0f;
        #pragma unroll
        for (int kt = 0; kt < 2; kt++)
            #pragma unroll
            for (int r = 0; r < 4; r++) {
                float e = exp2f(sacc[kt][qt][r] * C1);
                p[kt][r] = e;
                ps += e;
            }
        ps += __shfl_xor(ps, 16);
        ps += __shfl_xor(ps, 32);
        rl[qt] = 1.0f / ps;
        union { unsigned u[4]; s16x8 v8; } pu;
        pu.u[0] = pkbf(p[0][0], p[0][1]);
        pu.u[1] = pkbf(p[0][2], p[0][3]);
        pu.u[2] = pkbf(p[1][0], p[1][1]);
        pu.u[3] = pkbf(p[1][2], p[1][3]);
        pf[qt] = pu.v8;
    }

    #pragma unroll
    for (int qt = 0; qt < 2; qt++) {
        int qm = qt * 16 + lr;
        short* op = out + (size_t)((b * M + qm) * T + t) * D + h * 32;
        #pragma unroll
        for (int dt = 0; dt < 2; dt++) {
            const short* vb = &Xt[(h * 32 + dt * 16 + lr) * CTP + lg * 4];
            s16x4 a = *(const s16x4*)(vb);
            s16x4 bb = *(const s16x4*)(vb + 16);
            s16x8 vf = __builtin_shufflevector(a, bb, 0, 1, 2, 3, 4, 5, 6, 7);
            f32x4 Oa = __builtin_amdgcn_mfma_f32_16x16x32_bf16(vf, pf[qt], zacc, 0, 0, 0);
            union { unsigned u[2]; ushort4 s4; } ou;
            ou.u[0] = pkbf(Oa[0] * rl[qt], Oa[1] * rl[qt]);
            ou.u[1] = pkbf(Oa[2] * rl[qt], Oa[3] * rl[qt]);
            *(ushort4*)(op + dt * 16 + lg * 4) = ou.s4;
        }
    }
}

// ---------------- launch ----------------
extern "C" void kernel_launch(void* const* d_in, const int* in_sizes, int n_in,
                              void* d_out, int out_size, void* d_ws, size_t ws_size,
                              hipStream_t stream)
{
    (void)in_sizes; (void)n_in; (void)out_size; (void)ws_size;
    const float* xin = (const float*)d_in[0];
    const float* Wq  = (const float*)d_in[1];
    const float* bq  = (const float*)d_in[2];
    const float* Wk  = (const float*)d_in[3];
    const float* bk  = (const float*)d_in[4];
    const float* Wv  = (const float*)d_in[5];
    const float* bv  = (const float*)d_in[6];
    const float* Wfc = (const float*)d_in[7];
    const float* bfc = (const float*)d_in[8];
    const float* W1  = (const float*)d_in[9];
    const float* b1  = (const float*)d_in[10];
    const float* W2  = (const float*)d_in[11];
    const float* b2  = (const float*)d_in[12];
    const float* g1  = (const float*)d_in[13];
    const float* be1 = (const float*)d_in[14];
    const float* g2  = (const float*)d_in[15];
    const float* be2 = (const float*)d_in[16];
    const float* gf  = (const float*)d_in[17];
    const float* bef = (const float*)d_in[18];

    float* X = (float*)d_out;
    char* wsb = (char*)d_ws;
    const size_t SEGB = (size_t)NTOK * D * sizeof(float);   // 16 MiB
    const size_t SEGH = SEGB / 2;                           // 8 MiB bf16
    short* Qpb = (short*)(wsb + SEGH);
    short* Kpb = (short*)(wsb + 2 * SEGH);
    short* Vbf = (short*)(wsb + 3 * SEGH);
    short* CQb = (short*)(wsb + 4 * SEGH);
    short* CKb = (short*)(wsb + 5 * SEGH);

    // packed bf16 weight table (matches cvt_all_kernel layout)
    short* Wall = (short*)(wsb + 6 * SEGH);
    short* Wqb  = Wall;
    short* Wkb  = Wall + 32768;
    short* Wvb  = Wall + 65536;
    short* Wfcb = Wall + 98304;
    short* W1b  = Wall + 131072;
    short* W2b  = Wall + 262144;

    cvt_all_kernel<<<384, 256, 0, stream>>>(Wq, Wk, Wv, Wfc, W1, W2, Wall);

    for (int i = 0; i < 2; i++) {
        const float* xi  = i ? X : xin;   // LN1 input / FC residual
        qkv_ln_kernel<<<NTOK / 128, 512, 0, stream>>>(xi, g1 + i * D, be1 + i * D,
                                                      Wqb + i * D * D, Wkb + i * D * D, Wvb + i * D * D,
                                                      bq + i * D, bk + i * D, bv + i * D,
                                                      Qpb, Kpb, Vbf);
        ctx_mfma_kernel<<<dim3(B * M * (T / 64), 2), 256, 0, stream>>>(Qpb, CQb, Kpb, CKb);
        attn_mfma_kernel<<<B * M * H, 1024, 0, stream>>>(CQb, CKb, Vbf, Qpb);
        crossm_mfma_kernel<<<B * T, 256, 0, stream>>>(Qpb, Kpb);
        gemm_bf16_kernel<128><<<dim3(1, NTOK / 128), 512, 0, stream>>>(Kpb, Wfcb + i * D * D, bfc + i * D, xi, X, D);
        mlp_ln_kernel<<<NTOK / 64, 512, 0, stream>>>(X, g2 + i * D, be2 + i * D,
                                                     W1b + i * 4 * D * D, b1 + i * 4 * D,
                                                     W2b + i * 4 * D * D, b2 + i * D, X);
    }
    ln_kernel<<<NTOK / 4, 256, 0, stream>>>(X, X, gf, bef);
}

// Round 13
// 216.553 us; speedup vs baseline: 1.0647x; 1.0647x over previous
//
#include <hip/hip_runtime.h>
#include <hip/hip_bf16.h>
#include <math.h>

#define B 2
#define M 32
#define T 512
#define D 128
#define H 4
#define DK 32
#define NTOK (B*M*T)   /* 32768 rows */

using s16x8 = __attribute__((ext_vector_type(8))) short;
using s16x4 = __attribute__((ext_vector_type(4))) short;
using f32x4 = __attribute__((ext_vector_type(4))) float;

__device__ __forceinline__ short f2bf(float x) {
    union { float f; unsigned u; } a; a.f = x;
    unsigned r = a.u + 0x7fffu + ((a.u >> 16) & 1u);   // RNE
    return (short)(r >> 16);
}
__device__ __forceinline__ unsigned pkbf(float lo, float hi) {
    union { __hip_bfloat162 h; unsigned u; } c;
    c.h = __float22bfloat162_rn(float2{lo, hi});
    return c.u;
}

// ---------------- all weights fp32 -> bf16 in one dispatch ----------------
// dst layout: Wq[0,32768) Wk[32768,65536) Wv[65536,98304) Wfc[98304,131072)
//             W1[131072,262144) W2[262144,393216)
__global__ __launch_bounds__(256) void cvt_all_kernel(const float* __restrict__ Wq, const float* __restrict__ Wk,
                                                      const float* __restrict__ Wv, const float* __restrict__ Wfc,
                                                      const float* __restrict__ W1, const float* __restrict__ W2,
                                                      short* __restrict__ dst)
{
    int i = (blockIdx.x * 256 + threadIdx.x) * 4;
    if (i >= 393216) return;
    const float* src; int off;
    if (i < 131072) {
        int wsel = i >> 15; off = i & 32767;
        src = (wsel == 0) ? Wq : (wsel == 1) ? Wk : (wsel == 2) ? Wv : Wfc;
    } else if (i < 262144) { src = W1; off = i - 131072; }
    else                   { src = W2; off = i - 262144; }
    float4 v = *(const float4*)(src + off);
    ushort4 u;
    u.x = (unsigned short)f2bf(v.x); u.y = (unsigned short)f2bf(v.y);
    u.z = (unsigned short)f2bf(v.z); u.w = (unsigned short)f2bf(v.w);
    *(ushort4*)(dst + i) = u;
}

// ---------------- LayerNorm (final only): one wave per row of 128, fp32 out ----------------
__global__ __launch_bounds__(256) void ln_kernel(const float* __restrict__ in, float* __restrict__ outf,
                                                 const float* __restrict__ g, const float* __restrict__ b)
{
    int wave = threadIdx.x >> 6;
    int lane = threadIdx.x & 63;
    int row  = blockIdx.x * 4 + wave;
    const float* rp = in + (size_t)row * D;
    float v0 = rp[lane], v1 = rp[lane + 64];
    float s = v0 + v1, ss = v0 * v0 + v1 * v1;
    #pragma unroll
    for (int off = 32; off; off >>= 1) { s += __shfl_xor(s, off); ss += __shfl_xor(ss, off); }
    float mu  = s * (1.0f / 128.0f);
    float var = ss * (1.0f / 128.0f) - mu * mu;
    float rs  = rsqrtf(var + 1e-6f);
    float* op = outf + (size_t)row * D;
    op[lane]      = (v0 - mu) * rs * g[lane]      + b[lane];
    op[lane + 64] = (v1 - mu) * rs * g[lane + 64] + b[lane + 64];
}

#define KP 136

// LN staging helper: computes LN of row (rowBase+sr), cols sq*32..+31, writes bf16 into As.
#define LN_STAGE(XPTR, GPTR, BEPTR)                                              \
    {                                                                            \
        const float* xp = (XPTR) + (size_t)(rowBase + sr) * D + sq * 32;         \
        float4 xv[8];                                                            \
        _Pragma("unroll")                                                        \
        for (int j = 0; j < 8; j++) xv[j] = *(const float4*)(xp + j * 4);        \
        float s = 0.0f, ss = 0.0f;                                               \
        _Pragma("unroll")                                                        \
        for (int j = 0; j < 8; j++) {                                            \
            s  += xv[j].x + xv[j].y + xv[j].z + xv[j].w;                         \
            ss += xv[j].x*xv[j].x + xv[j].y*xv[j].y + xv[j].z*xv[j].z + xv[j].w*xv[j].w; \
        }                                                                        \
        s  += __shfl_xor(s, 1);  s  += __shfl_xor(s, 2);                         \
        ss += __shfl_xor(ss, 1); ss += __shfl_xor(ss, 2);                        \
        float mu  = s * (1.0f / 128.0f);                                         \
        float var = ss * (1.0f / 128.0f) - mu * mu;                              \
        float rs  = rsqrtf(var + 1e-6f);                                         \
        const float* gp  = (GPTR) + sq * 32;                                     \
        const float* bep = (BEPTR) + sq * 32;                                    \
        short* asd = &As[sr * KP + sq * 32];                                     \
        _Pragma("unroll")                                                        \
        for (int c = 0; c < 4; c++) {                                            \
            float4 a0 = xv[2*c], a1 = xv[2*c+1];                                 \
            float4 g0 = *(const float4*)(gp + c * 8);                            \
            float4 g1 = *(const float4*)(gp + c * 8 + 4);                        \
            float4 b0 = *(const float4*)(bep + c * 8);                           \
            float4 b1 = *(const float4*)(bep + c * 8 + 4);                       \
            union { unsigned u[4]; s16x8 v8; } pu;                               \
            pu.u[0] = pkbf((a0.x-mu)*rs*g0.x+b0.x, (a0.y-mu)*rs*g0.y+b0.y);      \
            pu.u[1] = pkbf((a0.z-mu)*rs*g0.z+b0.z, (a0.w-mu)*rs*g0.w+b0.w);      \
            pu.u[2] = pkbf((a1.x-mu)*rs*g1.x+b1.x, (a1.y-mu)*rs*g1.y+b1.y);      \
            pu.u[3] = pkbf((a1.z-mu)*rs*g1.z+b1.z, (a1.w-mu)*rs*g1.w+b1.w);      \
            *(s16x8*)(asd + c * 8) = pu.v8;                                      \
        }                                                                        \
    }

// ---------------- Fused LN + Q/K/V projections: A + ALL THREE W tiles staged once ----------------
__global__ __launch_bounds__(512) void qkv_ln_kernel(const float* __restrict__ X,
                                                     const float* __restrict__ g, const float* __restrict__ be,
                                                     const short* __restrict__ Wq, const short* __restrict__ Wk,
                                                     const short* __restrict__ Wv,
                                                     const float* __restrict__ bq, const float* __restrict__ bk,
                                                     const float* __restrict__ bv,
                                                     short* __restrict__ Qo, short* __restrict__ Ko,
                                                     short* __restrict__ Vo)
{
    __shared__ short As[128 * KP];
    __shared__ short Ws[3][128 * KP];
    const int tid = threadIdx.x;
    const int rowBase = blockIdx.x * 128;
    const int sr = tid >> 2, sq = tid & 3;
    const int w = tid >> 6, l = tid & 63;
    const int lg = l >> 4, lr = l & 15;
    const int wr = w >> 2, wc = w & 3;

    const short* wsrc[3] = { Wq, Wk, Wv };
    const float* bsrc[3] = { bq, bk, bv };
    short*       osrc[3] = { Qo, Ko, Vo };

    #pragma unroll
    for (int gsel = 0; gsel < 3; gsel++) {
        const short* wp = wsrc[gsel] + (size_t)sr * D + sq * 32;
        short* wsd = &Ws[gsel][sr * KP + sq * 32];
        #pragma unroll
        for (int i = 0; i < 4; i++) *(s16x8*)(wsd + i * 8) = *(const s16x8*)(wp + i * 8);
    }
    LN_STAGE(X, g, be)
    __syncthreads();

    for (int gsel = 0; gsel < 3; gsel++) {
        f32x4 acc[4][2];
        #pragma unroll
        for (int qi = 0; qi < 4; qi++)
            #pragma unroll
            for (int nj = 0; nj < 2; nj++)
                acc[qi][nj] = (f32x4){0.0f, 0.0f, 0.0f, 0.0f};
        #pragma unroll
        for (int kk = 0; kk < 4; kk++) {
            s16x8 af[4], bfr[2];
            #pragma unroll
            for (int qi = 0; qi < 4; qi++)
                af[qi] = *(const s16x8*)&As[(wr * 64 + qi * 16 + lr) * KP + kk * 32 + lg * 8];
            #pragma unroll
            for (int nj = 0; nj < 2; nj++)
                bfr[nj] = *(const s16x8*)&Ws[gsel][(wc * 32 + nj * 16 + lr) * KP + kk * 32 + lg * 8];
            #pragma unroll
            for (int qi = 0; qi < 4; qi++)
                #pragma unroll
                for (int nj = 0; nj < 2; nj++)
                    acc[qi][nj] = __builtin_amdgcn_mfma_f32_16x16x32_bf16(af[qi], bfr[nj], acc[qi][nj], 0, 0, 0);
        }
        #pragma unroll
        for (int nj = 0; nj < 2; nj++) {
            int col = wc * 32 + nj * 16 + lr;
            float bb = bsrc[gsel][col];
            #pragma unroll
            for (int qi = 0; qi < 4; qi++) {
                #pragma unroll
                for (int rr = 0; rr < 4; rr++) {
                    int row = rowBase + wr * 64 + qi * 16 + lg * 4 + rr;
                    osrc[gsel][(size_t)row * D + col] = f2bf(acc[qi][nj][rr] + bb);
                }
            }
        }
    }
}

// ---------------- Fused MLP: LN2 + W1/ReLU + W2 + residual; H lives in REGISTERS ----------------
// Swapped-operand trick (validated in attn/ctx): H^T = mfma(W1rows, Xrows) puts H[xrow][hcol]
// lane-local; bias+relu+pack in-register; O^T += mfma(W2_perm_frag, H_pack) with the
// permuted-k W2 read. 128-row tile, 512 thr, wave = 16 xrows. LDS 3x34.8 = 104 KB.
__global__ __launch_bounds__(512) void mlp_ln_kernel(const float* __restrict__ X,
                                                     const float* __restrict__ g, const float* __restrict__ be,
                                                     const short* __restrict__ W1, const float* __restrict__ b1,
                                                     const short* __restrict__ W2, const float* __restrict__ b2,
                                                     float* __restrict__ Xout)
{
    __shared__ short As[128 * KP];    // LN(X): 128 rows x 128
    __shared__ short W1s[128 * KP];   // W1 group: 128 hcols x 128 k
    __shared__ short W2s[128 * KP];   // W2 group: 128 ocols x 128 hcols
    const int tid = threadIdx.x;
    const int rowBase = blockIdx.x * 128;
    const int sr = tid >> 2, sq = tid & 3;
    const int w = tid >> 6, l = tid & 63;
    const int lg = l >> 4, lr = l & 15;
    f32x4 zacc = {0.0f, 0.0f, 0.0f, 0.0f};

    LN_STAGE(X, g, be)
    // stage group 0 weights
    {
        const short* p1 = W1 + (size_t)sr * D + sq * 32;
        short* d1 = &W1s[sr * KP + sq * 32];
        #pragma unroll
        for (int i = 0; i < 4; i++) *(s16x8*)(d1 + i * 8) = *(const s16x8*)(p1 + i * 8);
        const short* p2 = W2 + (size_t)sr * 512 + sq * 32;
        short* d2 = &W2s[sr * KP + sq * 32];
        #pragma unroll
        for (int i = 0; i < 4; i++) *(s16x8*)(d2 + i * 8) = *(const s16x8*)(p2 + i * 8);
    }
    __syncthreads();

    // X B-fragments for this wave's 16 rows
    s16x8 xf[4];
    #pragma unroll
    for (int kd = 0; kd < 4; kd++)
        xf[kd] = *(const s16x8*)&As[(w * 16 + lr) * KP + kd * 32 + lg * 8];

    f32x4 oacc[8];
    #pragma unroll
    for (int ot = 0; ot < 8; ot++) oacc[ot] = zacc;

    for (int gg = 0; gg < 4; gg++) {
        #pragma unroll
        for (int c = 0; c < 4; c++) {
            // phase 1: H^T tiles for 32 hcols (2 x 16)
            f32x4 hacc[2];
            #pragma unroll
            for (int hh = 0; hh < 2; hh++) {
                f32x4 a = zacc;
                #pragma unroll
                for (int kd = 0; kd < 4; kd++) {
                    s16x8 wf = *(const s16x8*)&W1s[(c * 32 + hh * 16 + lr) * KP + kd * 32 + lg * 8];
                    a = __builtin_amdgcn_mfma_f32_16x16x32_bf16(wf, xf[kd], a, 0, 0, 0);
                }
                hacc[hh] = a;
            }
            // bias + relu + pack (permuted-k order)
            int hbase = gg * 128 + c * 32;
            float4 b1v0 = *(const float4*)&b1[hbase + lg * 4];
            float4 b1v1 = *(const float4*)&b1[hbase + 16 + lg * 4];
            float p[8];
            p[0] = fmaxf(hacc[0][0] + b1v0.x, 0.0f);
            p[1] = fmaxf(hacc[0][1] + b1v0.y, 0.0f);
            p[2] = fmaxf(hacc[0][2] + b1v0.z, 0.0f);
            p[3] = fmaxf(hacc[0][3] + b1v0.w, 0.0f);
            p[4] = fmaxf(hacc[1][0] + b1v1.x, 0.0f);
            p[5] = fmaxf(hacc[1][1] + b1v1.y, 0.0f);
            p[6] = fmaxf(hacc[1][2] + b1v1.z, 0.0f);
            p[7] = fmaxf(hacc[1][3] + b1v1.w, 0.0f);
            union { unsigned u[4]; s16x8 v8; } pu;
            pu.u[0] = pkbf(p[0], p[1]);
            pu.u[1] = pkbf(p[2], p[3]);
            pu.u[2] = pkbf(p[4], p[5]);
            pu.u[3] = pkbf(p[6], p[7]);
            s16x8 pf = pu.v8;
            // phase 2: O^T += W2_perm . H_pack over all 8 output tiles
            #pragma unroll
            for (int ot = 0; ot < 8; ot++) {
                const short* vb = &W2s[(ot * 16 + lr) * KP + c * 32 + lg * 4];
                s16x4 a4 = *(const s16x4*)(vb);
                s16x4 b4 = *(const s16x4*)(vb + 16);
                s16x8 vf = __builtin_shufflevector(a4, b4, 0, 1, 2, 3, 4, 5, 6, 7);
                oacc[ot] = __builtin_amdgcn_mfma_f32_16x16x32_bf16(vf, pf, oacc[ot], 0, 0, 0);
            }
        }
        if (gg < 3) {
            __syncthreads();
            const short* p1 = W1 + (size_t)((gg + 1) * 128 + sr) * D + sq * 32;
            short* d1 = &W1s[sr * KP + sq * 32];
            #pragma unroll
            for (int i = 0; i < 4; i++) *(s16x8*)(d1 + i * 8) = *(const s16x8*)(p1 + i * 8);
            const short* p2 = W2 + (size_t)sr * 512 + (gg + 1) * 128 + sq * 32;
            short* d2 = &W2s[sr * KP + sq * 32];
            #pragma unroll
            for (int i = 0; i < 4; i++) *(s16x8*)(d2 + i * 8) = *(const s16x8*)(p2 + i * 8);
            __syncthreads();
        }
    }

    // epilogue: O^T lane -> X[xrow][ot*16 + lg*4 .. +3], add b2 + residual
    int xrow = rowBase + w * 16 + lr;
    float* xp = Xout + (size_t)xrow * D;
    #pragma unroll
    for (int ot = 0; ot < 8; ot++) {
        int col = ot * 16 + lg * 4;
        float4 res = *(const float4*)(xp + col);
        float4 bv  = *(const float4*)(b2 + col);
        float4 o;
        o.x = oacc[ot][0] + bv.x + res.x;
        o.y = oacc[ot][1] + bv.y + res.y;
        o.z = oacc[ot][2] + bv.z + res.z;
        o.w = oacc[ot][3] + bv.w + res.w;
        *(float4*)(xp + col) = o;
    }
}

// ---------------- bf16 MFMA GEMM (FC): out = A . W^T + bias + res ----------------
template<int DIN>
__global__ __launch_bounds__(512) void gemm_bf16_kernel(const short* __restrict__ A, const short* __restrict__ W,
                                                        const float* __restrict__ bias, const float* __restrict__ res,
                                                        float* __restrict__ outf, int Dout)
{
    __shared__ short As[128 * KP];
    __shared__ short Ws[128 * KP];
    const int tid = threadIdx.x;
    const int rowBase = blockIdx.y * 128;
    const int colBase = blockIdx.x * 128;
    const int sr = tid >> 2, sq = tid & 3;
    const int w = tid >> 6, l = tid & 63;
    const int lg = l >> 4, lr = l & 15;
    const int wr = w >> 2, wc = w & 3;

    f32x4 acc[4][2];
    #pragma unroll
    for (int qi = 0; qi < 4; qi++)
        #pragma unroll
        for (int nj = 0; nj < 2; nj++)
            acc[qi][nj] = (f32x4){0.0f, 0.0f, 0.0f, 0.0f};

    const short* ap = A + (size_t)(rowBase + sr) * DIN + sq * 32;
    const short* wp = W + (size_t)(colBase + sr) * DIN + sq * 32;
    short* asd = &As[sr * KP + sq * 32];
    short* wsd = &Ws[sr * KP + sq * 32];

    #pragma unroll
    for (int kt = 0; kt < DIN / 128; kt++) {
        s16x8 av[4], wv[4];
        #pragma unroll
        for (int i = 0; i < 4; i++) {
            av[i] = *(const s16x8*)(ap + kt * 128 + i * 8);
            wv[i] = *(const s16x8*)(wp + kt * 128 + i * 8);
        }
        if (kt) __syncthreads();
        #pragma unroll
        for (int i = 0; i < 4; i++) {
            *(s16x8*)(asd + i * 8) = av[i];
            *(s16x8*)(wsd + i * 8) = wv[i];
        }
        __syncthreads();
        #pragma unroll
        for (int kk = 0; kk < 4; kk++) {
            s16x8 af[4], bfr[2];
            #pragma unroll
            for (int qi = 0; qi < 4; qi++)
                af[qi] = *(const s16x8*)&As[(wr * 64 + qi * 16 + lr) * KP + kk * 32 + lg * 8];
            #pragma unroll
            for (int nj = 0; nj < 2; nj++)
                bfr[nj] = *(const s16x8*)&Ws[(wc * 32 + nj * 16 + lr) * KP + kk * 32 + lg * 8];
            #pragma unroll
            for (int qi = 0; qi < 4; qi++)
                #pragma unroll
                for (int nj = 0; nj < 2; nj++)
                    acc[qi][nj] = __builtin_amdgcn_mfma_f32_16x16x32_bf16(af[qi], bfr[nj], acc[qi][nj], 0, 0, 0);
        }
    }

    #pragma unroll
    for (int nj = 0; nj < 2; nj++) {
        int col = colBase + wc * 32 + nj * 16 + lr;
        float bb = bias[col];
        #pragma unroll
        for (int qi = 0; qi < 4; qi++) {
            #pragma unroll
            for (int rr = 0; rr < 4; rr++) {
                int row = rowBase + wr * 64 + qi * 16 + lg * 4 + rr;
                size_t o = (size_t)row * Dout + col;
                outf[o] = acc[qi][nj][rr] + bb + res[o];
            }
        }
    }
}

// ---------------- Context attention via banded MFMA (window L=16, d=128) ----------------
#define XSP 136
#define XTP 84
__global__ __launch_bounds__(256) void ctx_mfma_kernel(const short* __restrict__ in0, short* __restrict__ out0,
                                                       const short* __restrict__ in1, short* __restrict__ out1)
{
    __shared__ short Xs[80 * XSP];
    __shared__ short Xt[128 * XTP];

    const short* in  = blockIdx.y ? in1 : in0;
    short*       out = blockIdx.y ? out1 : out0;
    int bm = blockIdx.x >> 3;
    int t0 = (blockIdx.x & 7) * 64;
    int tid = threadIdx.x;
    const short* base = in + (size_t)bm * T * D;

    #pragma unroll
    for (int it = 0; it < 5; it++) {
        int idx = it * 256 + tid;
        int row = idx >> 4, c16 = idx & 15;
        int t = t0 - 16 + row;
        s16x8 v = {0, 0, 0, 0, 0, 0, 0, 0};
        if (t >= 0) v = *(const s16x8*)(base + (size_t)t * D + c16 * 8);
        *(s16x8*)&Xs[row * XSP + c16 * 8] = v;
    }
    __syncthreads();
    #pragma unroll
    for (int it = 0; it < 5; it++) {
        int task = it * 256 + tid;
        int g = task / 80, row = task % 80;
        s16x8 v = *(const s16x8*)&Xs[row * XSP + g * 8];
        #pragma unroll
        for (int j = 0; j < 8; j++) Xt[(g * 8 + j) * XTP + row] = v[j];
    }
    __syncthreads();

    int w = tid >> 6, l = tid & 63;
    int lg = l >> 4, lr = l & 15;
    f32x4 zacc = {0.0f, 0.0f, 0.0f, 0.0f};
    const float C1 = 0.0883883476483184f * 1.4426950408889634f;   // (1/sqrt(128))*log2e

    s16x8 qf[4];
    #pragma unroll
    for (int kd = 0; kd < 4; kd++)
        qf[kd] = *(const s16x8*)&Xs[(16 + w * 16 + lr) * XSP + kd * 32 + lg * 8];

    f32x4 sacc[2];
    #pragma unroll
    for (int s = 0; s < 2; s++) {
        f32x4 a = zacc;
        #pragma unroll
        for (int kd = 0; kd < 4; kd++) {
            s16x8 kf = *(const s16x8*)&Xs[(w * 16 + s * 16 + lr) * XSP + kd * 32 + lg * 8];
            a = __builtin_amdgcn_mfma_f32_16x16x32_bf16(kf, qf[kd], a, 0, 0, 0);
        }
        sacc[s] = a;
    }

    float p[2][4];
    float mx = -1e30f;
    #pragma unroll
    for (int s = 0; s < 2; s++)
        #pragma unroll
        for (int r = 0; r < 4; r++) {
            int dlt = s * 16 + lg * 4 + r - 16 - lr;   // k - q
            float val = (dlt >= -15 && dlt <= 0) ? sacc[s][r] : -1e30f;
            p[s][r] = val;
            mx = fmaxf(mx, val);
        }
    mx = fmaxf(mx, __shfl_xor(mx, 16));
    mx = fmaxf(mx, __shfl_xor(mx, 32));
    float mc = mx * C1;
    float ps = 0.0f;
    #pragma unroll
    for (int s = 0; s < 2; s++)
        #pragma unroll
        for (int r = 0; r < 4; r++) {
            float e = exp2f(fmaf(p[s][r], C1, -mc));
            p[s][r] = e;
            ps += e;
        }
    ps += __shfl_xor(ps, 16);
    ps += __shfl_xor(ps, 32);

    union { unsigned u[4]; s16x8 v8; } pu;
    pu.u[0] = pkbf(p[0][0], p[0][1]);
    pu.u[1] = pkbf(p[0][2], p[0][3]);
    pu.u[2] = pkbf(p[1][0], p[1][1]);
    pu.u[3] = pkbf(p[1][2], p[1][3]);
    s16x8 pf = pu.v8;

    float rl = 1.0f / ps;
    short* op = out + (size_t)(bm * T + t0 + w * 16 + lr) * D;
    #pragma unroll
    for (int dt = 0; dt < 8; dt++) {
        const short* vb = &Xt[(dt * 16 + lr) * XTP + w * 16 + lg * 4];
        s16x4 a = *(const s16x4*)(vb);
        s16x4 b = *(const s16x4*)(vb + 16);
        s16x8 vf = __builtin_shufflevector(a, b, 0, 1, 2, 3, 4, 5, 6, 7);
        f32x4 Oa = __builtin_amdgcn_mfma_f32_16x16x32_bf16(vf, pf, zacc, 0, 0, 0);
        union { unsigned u[2]; ushort4 s4; } ou;
        ou.u[0] = pkbf(Oa[0] * rl, Oa[1] * rl);
        ou.u[1] = pkbf(Oa[2] * rl, Oa[3] * rl);
        *(ushort4*)(op + dt * 16 + lg * 4) = ou.s4;
    }
}

// ---------------- Full attention per (b,m,h): fixed-max bf16 MFMA flash, 16 waves ----------------
#define KPAD 40
#define VTP  520
__global__ __launch_bounds__(1024) void attn_mfma_kernel(const short* __restrict__ q, const short* __restrict__ k,
                                                         const short* __restrict__ v, short* __restrict__ out)
{
    __shared__ short Ks[512 * KPAD];
    __shared__ short Vt[32 * VTP];

    int h  = blockIdx.x & 3;
    int bm = blockIdx.x >> 2;
    int tid = threadIdx.x;
    size_t headoff = (size_t)(bm * T) * D + h * DK;

    {
        int row = tid >> 1, half = tid & 1;
        const s16x8* kp8 = (const s16x8*)(k + headoff + (size_t)row * D + half * 16);
        s16x8 k0 = kp8[0], k1 = kp8[1];
        short* kd = &Ks[row * KPAD + half * 16];
        *(s16x8*)(kd)     = k0;
        *(s16x8*)(kd + 8) = k1;
        const s16x8* vp8 = (const s16x8*)(v + headoff + (size_t)row * D + half * 16);
        s16x8 v0 = vp8[0], v1 = vp8[1];
        #pragma unroll
        for (int d = 0; d < 8; d++) {
            Vt[(half * 16 + d) * VTP + row]     = v0[d];
            Vt[(half * 16 + 8 + d) * VTP + row] = v1[d];
        }
    }
    __syncthreads();

    int w = tid >> 6, l = tid & 63;
    int lg = l >> 4, lr = l & 15;
    int qw = w * 32;

    s16x8 qf[2];
    #pragma unroll
    for (int qi = 0; qi < 2; qi++)
        qf[qi] = *(const s16x8*)(q + headoff + (size_t)(qw + qi * 16 + lr) * D + lg * 8);

    f32x4 Oa[2][2];
    float lrow[2];
    #pragma unroll
    for (int qi = 0; qi < 2; qi++) {
        lrow[qi] = 0.0f;
        #pragma unroll
        for (int r = 0; r < 4; r++) { Oa[qi][0][r] = 0.0f; Oa[qi][1][r] = 0.0f; }
    }
    const float C1 = 0.17677669529663689f * 1.4426950408889634f;   // (1/sqrt(32))*log2e
    f32x4 zacc = {0.0f, 0.0f, 0.0f, 0.0f};

    for (int kt = 0; kt < 8; kt++) {
        int kb = kt * 64;
        s16x8 kf[2][2];
        #pragma unroll
        for (int s = 0; s < 2; s++)
            #pragma unroll
            for (int hh = 0; hh < 2; hh++)
                kf[s][hh] = *(const s16x8*)&Ks[(kb + s * 32 + hh * 16 + lr) * KPAD + lg * 8];
        s16x8 vf[2][2];
        #pragma unroll
        for (int dh = 0; dh < 2; dh++)
            #pragma unroll
            for (int s = 0; s < 2; s++) {
                const short* vb = &Vt[(dh * 16 + lr) * VTP + kb + s * 32 + lg * 4];
                s16x4 a = *(const s16x4*)(vb);
                s16x4 b = *(const s16x4*)(vb + 16);
                vf[dh][s] = __builtin_shufflevector(a, b, 0, 1, 2, 3, 4, 5, 6, 7);
            }
        #pragma unroll
        for (int qi = 0; qi < 2; qi++) {
            f32x4 sa[2][2];
            #pragma unroll
            for (int s = 0; s < 2; s++)
                #pragma unroll
                for (int hh = 0; hh < 2; hh++)
                    sa[s][hh] = __builtin_amdgcn_mfma_f32_16x16x32_bf16(kf[s][hh], qf[qi], zacc, 0, 0, 0);
            float p[2][8];
            float ps = 0.0f;
            #pragma unroll
            for (int s = 0; s < 2; s++)
                #pragma unroll
                for (int hh = 0; hh < 2; hh++)
                    #pragma unroll
                    for (int r = 0; r < 4; r++) {
                        float e = exp2f(sa[s][hh][r] * C1);
                        p[s][hh * 4 + r] = e;
                        ps += e;
                    }
            lrow[qi] += ps;
            s16x8 pf[2];
            #pragma unroll
            for (int s = 0; s < 2; s++) {
                union { unsigned u[4]; s16x8 v8; } pu;
                pu.u[0] = pkbf(p[s][0], p[s][1]);
                pu.u[1] = pkbf(p[s][2], p[s][3]);
                pu.u[2] = pkbf(p[s][4], p[s][5]);
                pu.u[3] = pkbf(p[s][6], p[s][7]);
                pf[s] = pu.v8;
            }
            #pragma unroll
            for (int dh = 0; dh < 2; dh++)
                #pragma unroll
                for (int s = 0; s < 2; s++)
                    Oa[qi][dh] = __builtin_amdgcn_mfma_f32_16x16x32_bf16(vf[dh][s], pf[s], Oa[qi][dh], 0, 0, 0);
        }
    }

    #pragma unroll
    for (int qi = 0; qi < 2; qi++) {
        float lv = lrow[qi];
        lv += __shfl_xor(lv, 16);
        lv += __shfl_xor(lv, 32);
        float rl = 1.0f / lv;
        int qrow = qw + qi * 16 + lr;
        short* op = out + headoff + (size_t)qrow * D;
        #pragma unroll
        for (int dh = 0; dh < 2; dh++) {
            union { unsigned u[2]; ushort4 s4; } ou;
            ou.u[0] = pkbf(Oa[qi][dh][0] * rl, Oa[qi][dh][1] * rl);
            ou.u[1] = pkbf(Oa[qi][dh][2] * rl, Oa[qi][dh][3] * rl);
            *(ushort4*)(op + dh * 16 + lg * 4) = ou.s4;
        }
    }
}

// ---------------- Cross-m attention per (b,t) via MFMA: 4 waves = 4 heads of 32x32 ----------------
#define CXP 136
#define CTP 36
__global__ __launch_bounds__(256) void crossm_mfma_kernel(const short* __restrict__ in, short* __restrict__ out)
{
    __shared__ short Xs[32 * CXP];
    __shared__ short Xt[128 * CTP];
    int b = blockIdx.x >> 9;
    int t = blockIdx.x & 511;
    int tid = threadIdx.x;

    #pragma unroll
    for (int it = 0; it < 2; it++) {
        int idx = it * 256 + tid;
        int m = idx >> 4, c16 = idx & 15;
        s16x8 v = *(const s16x8*)(in + (size_t)((b * M + m) * T + t) * D + c16 * 8);
        *(s16x8*)&Xs[m * CXP + c16 * 8] = v;
    }
    __syncthreads();
    #pragma unroll
    for (int it = 0; it < 2; it++) {
        int task = it * 256 + tid;
        int g = task >> 5, m = task & 31;
        s16x8 v = *(const s16x8*)&Xs[m * CXP + g * 8];
        #pragma unroll
        for (int j = 0; j < 8; j++) Xt[(g * 8 + j) * CTP + m] = v[j];
    }
    __syncthreads();

    int h = tid >> 6, l = tid & 63;
    int lg = l >> 4, lr = l & 15;
    f32x4 zacc = {0.0f, 0.0f, 0.0f, 0.0f};
    const float C1 = 0.17677669529663689f * 1.4426950408889634f;

    s16x8 xf[2];
    #pragma unroll
    for (int i = 0; i < 2; i++)
        xf[i] = *(const s16x8*)&Xs[(i * 16 + lr) * CXP + h * 32 + lg * 8];

    f32x4 sacc[2][2];
    #pragma unroll
    for (int kt = 0; kt < 2; kt++)
        #pragma unroll
        for (int qt = 0; qt < 2; qt++)
            sacc[kt][qt] = __builtin_amdgcn_mfma_f32_16x16x32_bf16(xf[kt], xf[qt], zacc, 0, 0, 0);

    s16x8 pf[2];
    float rl[2];
    #pragma unroll
    for (int qt = 0; qt < 2; qt++) {
        float p[2][4];
        float ps = 0.0f;
        #pragma unroll
        for (int kt = 0; kt < 2; kt++)
            #pragma unroll
            for (int r = 0; r < 4; r++) {
                float e = exp2f(sacc[kt][qt][r] * C1);
                p[kt][r] = e;
                ps += e;
            }
        ps += __shfl_xor(ps, 16);
        ps += __shfl_xor(ps, 32);
        rl[qt] = 1.0f / ps;
        union { unsigned u[4]; s16x8 v8; } pu;
        pu.u[0] = pkbf(p[0][0], p[0][1]);
        pu.u[1] = pkbf(p[0][2], p[0][3]);
        pu.u[2] = pkbf(p[1][0], p[1][1]);
        pu.u[3] = pkbf(p[1][2], p[1][3]);
        pf[qt] = pu.v8;
    }

    #pragma unroll
    for (int qt = 0; qt < 2; qt++) {
        int qm = qt * 16 + lr;
        short* op = out + (size_t)((b * M + qm) * T + t) * D + h * 32;
        #pragma unroll
        for (int dt = 0; dt < 2; dt++) {
            const short* vb = &Xt[(h * 32 + dt * 16 + lr) * CTP + lg * 4];
            s16x4 a = *(const s16x4*)(vb);
            s16x4 bb = *(const s16x4*)(vb + 16);
            s16x8 vf = __builtin_shufflevector(a, bb, 0, 1, 2, 3, 4, 5, 6, 7);
            f32x4 Oa = __builtin_amdgcn_mfma_f32_16x16x32_bf16(vf, pf[qt], zacc, 0, 0, 0);
            union { unsigned u[2]; ushort4 s4; } ou;
            ou.u[0] = pkbf(Oa[0] * rl[qt], Oa[1] * rl[qt]);
            ou.u[1] = pkbf(Oa[2] * rl[qt], Oa[3] * rl[qt]);
            *(ushort4*)(op + dt * 16 + lg * 4) = ou.s4;
        }
    }
}

// ---------------- launch ----------------
extern "C" void kernel_launch(void* const* d_in, const int* in_sizes, int n_in,
                              void* d_out, int out_size, void* d_ws, size_t ws_size,
                              hipStream_t stream)
{
    (void)in_sizes; (void)n_in; (void)out_size; (void)ws_size;
    const float* xin = (const float*)d_in[0];
    const float* Wq  = (const float*)d_in[1];
    const float* bq  = (const float*)d_in[2];
    const float* Wk  = (const float*)d_in[3];
    const float* bk  = (const float*)d_in[4];
    const float* Wv  = (const float*)d_in[5];
    const float* bv  = (const float*)d_in[6];
    const float* Wfc = (const float*)d_in[7];
    const float* bfc = (const float*)d_in[8];
    const float* W1  = (const float*)d_in[9];
    const float* b1  = (const float*)d_in[10];
    const float* W2  = (const float*)d_in[11];
    const float* b2  = (const float*)d_in[12];
    const float* g1  = (const float*)d_in[13];
    const float* be1 = (const float*)d_in[14];
    const float* g2  = (const float*)d_in[15];
    const float* be2 = (const float*)d_in[16];
    const float* gf  = (const float*)d_in[17];
    const float* bef = (const float*)d_in[18];

    float* X = (float*)d_out;
    char* wsb = (char*)d_ws;
    const size_t SEGB = (size_t)NTOK * D * sizeof(float);   // 16 MiB
    const size_t SEGH = SEGB / 2;                           // 8 MiB bf16
    short* Qpb = (short*)(wsb + SEGH);
    short* Kpb = (short*)(wsb + 2 * SEGH);
    short* Vbf = (short*)(wsb + 3 * SEGH);
    short* CQb = (short*)(wsb + 4 * SEGH);
    short* CKb = (short*)(wsb + 5 * SEGH);

    // packed bf16 weight table (matches cvt_all_kernel layout)
    short* Wall = (short*)(wsb + 6 * SEGH);
    short* Wqb  = Wall;
    short* Wkb  = Wall + 32768;
    short* Wvb  = Wall + 65536;
    short* Wfcb = Wall + 98304;
    short* W1b  = Wall + 131072;
    short* W2b  = Wall + 262144;

    cvt_all_kernel<<<384, 256, 0, stream>>>(Wq, Wk, Wv, Wfc, W1, W2, Wall);

    for (int i = 0; i < 2; i++) {
        const float* xi  = i ? X : xin;   // LN1 input / FC residual
        qkv_ln_kernel<<<NTOK / 128, 512, 0, stream>>>(xi, g1 + i * D, be1 + i * D,
                                                      Wqb + i * D * D, Wkb + i * D * D, Wvb + i * D * D,
                                                      bq + i * D, bk + i * D, bv + i * D,
                                                      Qpb, Kpb, Vbf);
        ctx_mfma_kernel<<<dim3(B * M * (T / 64), 2), 256, 0, stream>>>(Qpb, CQb, Kpb, CKb);
        attn_mfma_kernel<<<B * M * H, 1024, 0, stream>>>(CQb, CKb, Vbf, Qpb);
        crossm_mfma_kernel<<<B * T, 256, 0, stream>>>(Qpb, Kpb);
        gemm_bf16_kernel<128><<<dim3(1, NTOK / 128), 512, 0, stream>>>(Kpb, Wfcb + i * D * D, bfc + i * D, xi, X, D);
        mlp_ln_kernel<<<NTOK / 128, 512, 0, stream>>>(X, g2 + i * D, be2 + i * D,
                                                      W1b + i * 4 * D * D, b1 + i * 4 * D,
                                                      W2b + i * 4 * D * D, b2 + i * D, X);
    }
    ln_kernel<<<NTOK / 4, 256, 0, stream>>>(X, X, gf, bef);
}